// Round 13
// baseline (5559.635 us; speedup 1.0000x reference)
//
#include <hip/hip_runtime.h>
#include <cstdint>
#include <cstddef>

#define DEVI __device__ __forceinline__

typedef __attribute__((ext_vector_type(8))) short bf16x8;
typedef __attribute__((ext_vector_type(4))) float f32x4;
typedef unsigned short ushort_t;
typedef unsigned int uint_t;

// problem dims (fixed)
constexpr int NB = 64;    // batch
constexpr int NTT = 512;  // seq len
constexpr int NI = 512;   // input feat
constexpr int NH = 1024;  // hidden
constexpr int NA = 512;   // out feat
constexpr int NG = 4096;  // 4*NH
constexpr int CHUNK = 64; // scan chunk (timesteps per launch)

DEVI float bf2f(ushort_t u) { union { uint_t i; float f; } v; v.i = ((uint_t)u) << 16; return v.f; }
DEVI ushort_t f2bf(float f) {
  union { float f; uint_t i; } v; v.f = f;
  uint_t x = v.i;
  return (ushort_t)((x + 0x7fffu + ((x >> 16) & 1u)) >> 16);
}

// clamped fast tanh: safe for |x| large (clamp before exp), bf16-accurate
DEVI float tanh_f(float x) {
  x = fminf(fmaxf(x, -15.f), 15.f);
  float e = __expf(2.f * x);
  return (e - 1.f) / (e + 1.f);
}

DEVI void gload_lds16(const void* g, void* l) {
  __builtin_amdgcn_global_load_lds((__attribute__((address_space(1))) void*)g,
                                   (__attribute__((address_space(3))) void*)l, 16, 0, 0);
}

// ---------------- cast fp32 -> bf16 ----------------
__global__ __launch_bounds__(256) void cast_f32_bf16(const float* __restrict__ in,
                                                     ushort_t* __restrict__ out, int n) {
  int i = (blockIdx.x * 256 + threadIdx.x) * 4;
  if (i >= n) return;
  float4 v = *(const float4*)(in + i);
  ushort4 o;
  o.x = f2bf(v.x); o.y = f2bf(v.y); o.z = f2bf(v.z); o.w = f2bf(v.w);
  *(ushort4*)(out + i) = o;
}

// ---------------- generic NT GEMM: C[M,N] = A[M,K] * B[N,K]^T ----------------
// MODE 0: fp32 out, +bias0 (fc3) | MODE 1: bf16 out, tanh (fc1) |
// MODE 2: chunked gx, scatter to gxc[tl][wg][b][g*16+u]
template <int MODE>
__global__ __launch_bounds__(256) void gemm_nt(const short* __restrict__ A,
                                               const short* __restrict__ Bm,
                                               const float* __restrict__ bias0,
                                               const float* __restrict__ bias1,
                                               void* __restrict__ Cout,
                                               int M, int N, int K, int t0) {
  __shared__ short As[128 * 32];
  __shared__ short Bs[128 * 32];
  const int tid = threadIdx.x;
  const int wave = tid >> 6, lane = tid & 63;
  const int m0 = blockIdx.y * 128, n0 = blockIdx.x * 128;
  const int wr = wave >> 1, wc = wave & 1;

  f32x4 zero = {0.f, 0.f, 0.f, 0.f};
  f32x4 acc[4][4];
#pragma unroll
  for (int i = 0; i < 4; ++i)
#pragma unroll
    for (int j = 0; j < 4; ++j) acc[i][j] = zero;

  const int lrow = lane >> 2;
  const int lk = (lane & 3) * 8;

  for (int kt = 0; kt < K; kt += 32) {
#pragma unroll
    for (int c = 0; c < 2; ++c) {
      int q = wave + 4 * c;
      int row = m0 + q * 16 + lrow;
      long arow = (MODE == 2) ? ((long)(row >> 6) * NTT + t0 + (row & 63)) : (long)row;
      gload_lds16(A + arow * K + kt + lk, As + q * 512);
      gload_lds16(Bm + (long)(n0 + q * 16 + lrow) * K + kt + lk, Bs + q * 512);
    }
    __syncthreads();

    bf16x8 av[4], bv[4];
#pragma unroll
    for (int i = 0; i < 4; ++i) {
      int row = wr * 64 + i * 16 + (lane & 15);
      av[i] = *(const bf16x8*)(As + row * 32 + (lane >> 4) * 8);
    }
#pragma unroll
    for (int j = 0; j < 4; ++j) {
      int col = wc * 64 + j * 16 + (lane & 15);
      bv[j] = *(const bf16x8*)(Bs + col * 32 + (lane >> 4) * 8);
    }
#pragma unroll
    for (int i = 0; i < 4; ++i)
#pragma unroll
      for (int j = 0; j < 4; ++j)
        acc[i][j] = __builtin_amdgcn_mfma_f32_16x16x32_bf16(av[i], bv[j], acc[i][j], 0, 0, 0);
    __syncthreads();
  }

  const int fq = lane >> 4, fr = lane & 15;
#pragma unroll
  for (int i = 0; i < 4; ++i) {
#pragma unroll
    for (int j = 0; j < 4; ++j) {
      int gcol = n0 + wc * 64 + j * 16 + fr;
      float bsum = bias0[gcol];
      if (MODE == 2) bsum += bias1[gcol];
#pragma unroll
      for (int r = 0; r < 4; ++r) {
        int gm = m0 + wr * 64 + i * 16 + fq * 4 + r;
        float v = acc[i][j][r] + bsum;
        if (MODE == 0) {
          ((float*)Cout)[(long)gm * N + gcol] = v;
        } else if (MODE == 1) {
          ((ushort_t*)Cout)[(long)gm * N + gcol] = f2bf(tanhf(v));
        } else {
          int b = gm >> 6, tl = gm & 63;
          int wgp = (gcol >> 4) & 63, g = gcol >> 10, u = gcol & 15;
          ((ushort_t*)Cout)[((((long)tl * 64 + wgp) * 64 + b) << 6) + g * 16 + u] = f2bf(v);
        }
      }
    }
  }
}

// ---------------- persistent LSTM scan: dual-group time-interleaved pipeline ----------------
// 64 WGs x 512 threads (8 waves). Batches split into groups A=0..31, B=32..63 with
// separate hseq chains / flags / c-state. Each WG alternates phases A,B per tl.
// The phase for group X overlaps: (a) wave7's early flag-gather for group Y,
// (b) Y's h-load issue (mid-phase, lands during X's gates/publish),
// so detect latency and cold-load latency hide under compute. No global barrier.
// Waves: g = wave>>1 (K-quarter of 256 cols), w2 = wave&1 (16-batch slab in group).
// Weights fragment-ordered in LDS (conflict-free); 3 LDS partial buffers for g1-3.
__global__ __launch_bounds__(512, 2) void lstm_scan(const ushort_t* __restrict__ whh,
                                                    const ushort_t* __restrict__ gxc,  // [CHUNK][64][NB][64]
                                                    ushort_t* __restrict__ hseq,       // [2][CHUNK+1][32][NH]
                                                    float* __restrict__ cbuf,          // [NB][NH]
                                                    ushort_t* __restrict__ hs,         // [NB][NTT][NH]
                                                    uint_t* __restrict__ flags,        // [2][64*32]
                                                    int t0, uint_t tbase) {
  extern __shared__ char smem[];
  float* pre = (float*)(smem + 131072);                 // 3 x [32][65] fp32
  uint_t* ctrl = (uint_t*)(smem + 131072 + 24960);      // [0]=cnt, [1]=goA, [2]=goB
  const int wg = blockIdx.x, tid = threadIdx.x;
  const int wave = tid >> 6, lane = tid & 63;
  const int g = wave >> 1, w2 = wave & 1;
  const int fq = lane >> 4, fr = lane & 15;
  const int bb = w2 * 16, lane16 = lane * 16;
  const size_t HSG = (size_t)(CHUNK + 1) * 32 * NH;
  f32x4 zero = {0.f, 0.f, 0.f, 0.f};

  // stage weights into fragment-ordered LDS
  for (int idx = tid; idx < 64 * 128; idx += 512) {
    int n = idx >> 7, kc = idx & 127;
    int grow = (n >> 4) * NH + wg * 16 + (n & 15);
    bf16x8 w = *(const bf16x8*)(whh + (long)grow * NH + kc * 8);
    int frag = ((kc >> 2) * 4 + (n >> 4)) * 64 + (kc & 3) * 16 + (n & 15);
    *(bf16x8*)(smem + frag * 16) = w;
  }
  if (tid == 0) { ctrl[0] = 0; ctrl[1] = 0; ctrl[2] = 0; }

  // init slot0 of both groups (own 16 units only): 2 groups x 32 b x 8 uint
  if (t0 == 0) {
    int gs = tid >> 8, rem = tid & 255;
    int b = rem >> 3, up = rem & 7;
    uint_t* p = (uint_t*)(hseq + (size_t)gs * HSG + (size_t)b * NH + wg * 16) + up;
    __hip_atomic_store(p, 0u, __ATOMIC_RELAXED, __HIP_MEMORY_SCOPE_AGENT);
  }
  // c-state: g0 lanes own (group gs, batch bb+fq*4+r, unit fr)
  float ccA[4], ccB[4];
  if (g == 0) {
#pragma unroll
    for (int r = 0; r < 4; ++r) {
      int bl = bb + fq * 4 + r;
      ccA[r] = (t0 == 0) ? 0.f : cbuf[(size_t)(bl) * NH + wg * 16 + fr];
      ccB[r] = (t0 == 0) ? 0.f : cbuf[(size_t)(32 + bl) * NH + wg * 16 + fr];
    }
  }

  // prologue: drain inits, publish own readiness for both groups, wave7 polls
  asm volatile("s_waitcnt vmcnt(0)" ::: "memory");
  __syncthreads();
  if (tid == 0) {
    __hip_atomic_store(flags + wg * 32, tbase + 1, __ATOMIC_RELAXED, __HIP_MEMORY_SCOPE_AGENT);
    __hip_atomic_store(flags + 64 * 32 + wg * 32, tbase + 1, __ATOMIC_RELAXED, __HIP_MEMORY_SCOPE_AGENT);
  }
  if (wave == 7) {
#pragma unroll
    for (int s = 0; s < 2; ++s) {
      uint_t* fp = flags + s * 64 * 32 + lane * 32;
      for (;;) {
        uint_t v = __hip_atomic_load(fp, __ATOMIC_RELAXED, __HIP_MEMORY_SCOPE_AGENT);
        if (__all(v >= tbase + 1)) break;
        __builtin_amdgcn_s_sleep(1);
      }
      if (lane == 0)
        __hip_atomic_store(&ctrl[1 + s], tbase + 1, __ATOMIC_RELAXED, __HIP_MEMORY_SCOPE_WORKGROUP);
    }
  }
  __syncthreads();
  __builtin_amdgcn_fence(__ATOMIC_ACQUIRE, "agent");  // drop stale hseq lines

  bf16x8 aregA[8], aregB[8];
  ushort_t gxrA[16], gxrB[16];
  // issue aregA(slot0); gx for A0 and B0
  {
    const ushort_t* hc = hseq + 0 * HSG;  // A slot0
#pragma unroll
    for (int ks = 0; ks < 8; ++ks) {
      int ksg = g * 8 + ((ks + wg) & 7);
      aregA[ks] = *(const bf16x8*)(hc + (bb + fr) * NH + ksg * 32 + fq * 8);
    }
  }
  if (g == 0) {
    const ushort_t* src = gxc + ((size_t)0 * 64 + wg) * 4096;
#pragma unroll
    for (int nt = 0; nt < 4; ++nt)
#pragma unroll
      for (int r = 0; r < 4; ++r) {
        int bl = bb + fq * 4 + r;
        gxrA[nt * 4 + r] = src[(bl << 6) + nt * 16 + fr];
        gxrB[nt * 4 + r] = src[((32 + bl) << 6) + nt * 16 + fr];
      }
  }

  auto phase = [&](int xs, bf16x8* aX, bf16x8* aY, ushort_t* gxX, float* ccX, int tl) {
    const int ysel = xs ^ 1;
    const int yslot = (xs == 0) ? tl : tl + 1;
    const uint_t ytag = tbase + 1 + yslot;
    const uint_t ptag = tbase + 2 + tl;
    uint_t* flgY = flags + ysel * 64 * 32;
    uint_t* flgX = flags + xs * 64 * 32;
    ushort_t* hsX = hseq + (size_t)xs * HSG;
    const ushort_t* hcY = hseq + (size_t)ysel * HSG + (size_t)yslot * 32 * NH;

    uint_t gv = 0;
    if (wave == 7)  // early gather: lands during MFMA
      gv = __hip_atomic_load(flgY + lane * 32, __ATOMIC_RELAXED, __HIP_MEMORY_SCOPE_AGENT);

    f32x4 acc[4] = {zero, zero, zero, zero};
#pragma unroll
    for (int ks = 0; ks < 8; ++ks) {
      int ksg = g * 8 + ((ks + wg) & 7);
#pragma unroll
      for (int nt = 0; nt < 4; ++nt) {
        bf16x8 w = *(const bf16x8*)(smem + ((ksg * 4 + nt) << 10) + lane16);
        acc[nt] = __builtin_amdgcn_mfma_f32_16x16x32_bf16(aX[ks], w, acc[nt], 0, 0, 0);
      }
    }
    // K-quarter partials -> LDS (g1..g3)
    if (g > 0) {
      float* pg = pre + (g - 1) * 32 * 65;
#pragma unroll
      for (int nt = 0; nt < 4; ++nt)
#pragma unroll
        for (int r = 0; r < 4; ++r)
          pg[(bb + fq * 4 + r) * 65 + nt * 16 + fr] = acc[nt][r];
    }
    // wave7: finish poll, broadcast go
    if (wave == 7) {
      for (;;) {
        if (__all(gv >= ytag)) break;
        __builtin_amdgcn_s_sleep(1);
        gv = __hip_atomic_load(flgY + lane * 32, __ATOMIC_RELAXED, __HIP_MEMORY_SCOPE_AGENT);
      }
      if (lane == 0)
        __hip_atomic_store(&ctrl[1 + ysel], ytag, __ATOMIC_RELAXED, __HIP_MEMORY_SCOPE_WORKGROUP);
    }
    // non-g0 waves: wait go, issue next group's h loads (land during gates/publish)
    if (g != 0) {
      while (__hip_atomic_load(&ctrl[1 + ysel], __ATOMIC_RELAXED, __HIP_MEMORY_SCOPE_WORKGROUP) < ytag)
        __builtin_amdgcn_s_sleep(1);
#pragma unroll
      for (int ks = 0; ks < 8; ++ks) {
        int ksg = g * 8 + ((ks + wg) & 7);
        aY[ks] = *(const bf16x8*)(hcY + (bb + fr) * NH + ksg * 32 + fq * 8);
      }
    }
    __syncthreads();  // sync1: partials ready
    if (g == 0) {
      uint_t hp[4];
#pragma unroll
      for (int r = 0; r < 4; ++r) {
        int bl = bb + fq * 4 + r;
        float xi = acc[0][r] + pre[bl * 65 + fr] + pre[2080 + bl * 65 + fr] + pre[4160 + bl * 65 + fr] + bf2f(gxX[r]);
        float xf = acc[1][r] + pre[bl * 65 + 16 + fr] + pre[2080 + bl * 65 + 16 + fr] + pre[4160 + bl * 65 + 16 + fr] + bf2f(gxX[4 + r]);
        float xg = acc[2][r] + pre[bl * 65 + 32 + fr] + pre[2080 + bl * 65 + 32 + fr] + pre[4160 + bl * 65 + 32 + fr] + bf2f(gxX[8 + r]);
        float xo = acc[3][r] + pre[bl * 65 + 48 + fr] + pre[2080 + bl * 65 + 48 + fr] + pre[4160 + bl * 65 + 48 + fr] + bf2f(gxX[12 + r]);
        float ig = 1.f / (1.f + __expf(-xi));
        float fg = 1.f / (1.f + __expf(-xf));
        float gg = tanh_f(xg);
        float og = 1.f / (1.f + __expf(-xo));
        ccX[r] = fg * ccX[r] + ig * gg;
        float hv = og * tanh_f(ccX[r]);
        uint_t hb = (uint_t)f2bf(hv);
        uint_t other = (uint_t)__shfl_xor((int)hb, 1, 64);
        hp[r] = hb | (other << 16);  // valid on even fr
        if (!(fr & 1)) {
          uint_t* hdst = (uint_t*)(hsX + (size_t)(tl + 1) * 32 * NH + (size_t)bl * NH + wg * 16 + fr);
          __hip_atomic_store(hdst, hp[r], __ATOMIC_RELAXED, __HIP_MEMORY_SCOPE_AGENT);
          if (tl == CHUNK - 1) {
            uint_t* h0 = (uint_t*)(hsX + (size_t)bl * NH + wg * 16 + fr);
            __hip_atomic_store(h0, hp[r], __ATOMIC_RELAXED, __HIP_MEMORY_SCOPE_AGENT);
          }
        }
      }
      asm volatile("s_waitcnt vmcnt(0)" ::: "memory");  // slice at LLC
      if (lane == 0) {
        uint_t old = atomicAdd(&ctrl[0], 1u);
        if (old & 1)
          __hip_atomic_store(flgX + wg * 32, ptag, __ATOMIC_RELAXED, __HIP_MEMORY_SCOPE_AGENT);
      }
      // now issue next group's h loads + next gx + hs (off release path)
      while (__hip_atomic_load(&ctrl[1 + ysel], __ATOMIC_RELAXED, __HIP_MEMORY_SCOPE_WORKGROUP) < ytag)
        __builtin_amdgcn_s_sleep(1);
#pragma unroll
      for (int ks = 0; ks < 8; ++ks) {
        int ksg = g * 8 + ((ks + wg) & 7);
        aY[ks] = *(const bf16x8*)(hcY + (bb + fr) * NH + ksg * 32 + fq * 8);
      }
      if (tl + 1 < CHUNK) {
        const ushort_t* src = gxc + ((size_t)(tl + 1) * 64 + wg) * 4096;
#pragma unroll
        for (int nt = 0; nt < 4; ++nt)
#pragma unroll
          for (int r = 0; r < 4; ++r)
            gxX[nt * 4 + r] = src[((xs * 32 + bb + fq * 4 + r) << 6) + nt * 16 + fr];
      }
      if (!(fr & 1)) {
#pragma unroll
        for (int r = 0; r < 4; ++r)
          *(uint_t*)(hs + ((size_t)(xs * 32 + bb + fq * 4 + r) * NTT + t0 + tl) * NH + wg * 16 + fr) = hp[r];
      }
    }
    __syncthreads();  // sync2: pre free for next phase
  };

  for (int tl = 0; tl < CHUNK; ++tl) {
    phase(0, aregA, aregB, gxrA, ccA, tl);
    phase(1, aregB, aregA, gxrB, ccB, tl);
  }
  // persist c
  if (g == 0) {
#pragma unroll
    for (int r = 0; r < 4; ++r) {
      int bl = bb + fq * 4 + r;
      cbuf[(size_t)bl * NH + wg * 16 + fr] = ccA[r];
      cbuf[(size_t)(32 + bl) * NH + wg * 16 + fr] = ccB[r];
    }
  }
}

// ---------------- host ----------------
extern "C" void kernel_launch(void* const* d_in, const int* in_sizes, int n_in,
                              void* d_out, int out_size, void* d_ws, size_t ws_size,
                              hipStream_t stream) {
  const float* x = (const float*)d_in[0];
  const float* w1 = (const float*)d_in[1];
  const float* b1 = (const float*)d_in[2];
  const float* w_ih = (const float*)d_in[3];
  const float* w_hh = (const float*)d_in[4];
  const float* b_ih = (const float*)d_in[5];
  const float* b_hh = (const float*)d_in[6];
  const float* w3 = (const float*)d_in[7];
  const float* b3 = (const float*)d_in[8];

  char* ws = (char*)d_ws;
  size_t off = 0;
  auto alloc = [&](size_t bytes) {
    char* p = ws + off;
    off += (bytes + 255) & ~(size_t)255;
    return p;
  };
  ushort_t* w1b = (ushort_t*)alloc(sizeof(ushort_t) * NH * NI);
  ushort_t* wihb = (ushort_t*)alloc(sizeof(ushort_t) * NG * NH);
  ushort_t* whhb = (ushort_t*)alloc(sizeof(ushort_t) * NG * NH);
  ushort_t* w3b = (ushort_t*)alloc(sizeof(ushort_t) * NA * NH);
  ushort_t* fb = (ushort_t*)alloc(sizeof(ushort_t) * (size_t)NB * NTT * NH);  // f, then hs (in-place)
  float* cbuf = (float*)alloc(sizeof(float) * NB * NH);
  uint_t* flags = (uint_t*)alloc(sizeof(uint_t) * 2 * 64 * 32);
  if (off > ws_size) {
    hipMemsetAsync(d_out, 0xFF, 256, stream);  // NaN sentinel: ws too small
    return;
  }

  // scratch carved out of d_out (dead before fc3 writes d_out):
  ushort_t* xb = (ushort_t*)d_out;                           // bf16 x for fc1
  ushort_t* hseq = (ushort_t*)d_out;                         // [2][CHUNK+1][32][NH] = 8.5MB
  ushort_t* gxc = (ushort_t*)d_out + (size_t)NB * NTT * NI;  // [CHUNK][64][NB][64]

  auto cast = [&](const float* src, ushort_t* dst, int n) {
    cast_f32_bf16<<<dim3((n / 4 + 255) / 256), dim3(256), 0, stream>>>(src, dst, n);
  };
  cast(x, xb, NB * NTT * NI);
  cast(w1, w1b, NH * NI);
  cast(w_ih, wihb, NG * NH);
  cast(w_hh, whhb, NG * NH);
  cast(w3, w3b, NA * NH);

  // fc1 + tanh -> f (bf16)
  gemm_nt<1><<<dim3(NH / 128, NB * NTT / 128), dim3(256), 0, stream>>>(
      (const short*)xb, (const short*)w1b, b1, nullptr, fb, NB * NTT, NH, NI, 0);

  hipMemsetAsync(flags, 0, sizeof(uint_t) * 2 * 64 * 32, stream);
  int ldsz = 131072 + 24960 + 16;
  hipFuncSetAttribute(reinterpret_cast<const void*>(&lstm_scan),
                      hipFuncAttributeMaxDynamicSharedMemorySize, ldsz);

  for (int chunk = 0; chunk < NTT / CHUNK; ++chunk) {
    int t0 = chunk * CHUNK;
    gemm_nt<2><<<dim3(NG / 128, NB * CHUNK / 128), dim3(256), 0, stream>>>(
        (const short*)fb, (const short*)wihb, b_ih, b_hh, gxc, NB * CHUNK, NG, NH, t0);
    lstm_scan<<<dim3(64), dim3(512), ldsz, stream>>>(
        whhb, gxc, hseq, cbuf, fb, flags, t0, (uint_t)(chunk * (CHUNK + 1)));
  }

  // fc3 head -> d_out (fp32)
  gemm_nt<0><<<dim3(NA / 128, NB * NTT / 128), dim3(256), 0, stream>>>(
      (const short*)fb, (const short*)w3b, b3, nullptr, d_out, NB * NTT, NA, NH, 0);
}

// Round 14
// 3869.020 us; speedup vs baseline: 1.4370x; 1.4370x over previous
//
#include <hip/hip_runtime.h>
#include <cstdint>
#include <cstddef>

#define DEVI __device__ __forceinline__

typedef __attribute__((ext_vector_type(8))) short bf16x8;
typedef __attribute__((ext_vector_type(4))) float f32x4;
typedef unsigned short ushort_t;
typedef unsigned int uint_t;

// problem dims (fixed)
constexpr int NB = 64;    // batch
constexpr int NTT = 512;  // seq len
constexpr int NI = 512;   // input feat
constexpr int NH = 1024;  // hidden
constexpr int NA = 512;   // out feat
constexpr int NG = 4096;  // 4*NH

DEVI float bf2f(ushort_t u) { union { uint_t i; float f; } v; v.i = ((uint_t)u) << 16; return v.f; }
DEVI ushort_t f2bf(float f) {
  union { float f; uint_t i; } v; v.f = f;
  uint_t x = v.i;
  return (ushort_t)((x + 0x7fffu + ((x >> 16) & 1u)) >> 16);
}

// clamped fast tanh: safe for |x| large (clamp before exp), bf16-accurate
DEVI float tanh_f(float x) {
  x = fminf(fmaxf(x, -15.f), 15.f);
  float e = __expf(2.f * x);
  return (e - 1.f) / (e + 1.f);
}

DEVI void gload_lds16(const void* g, void* l) {
  __builtin_amdgcn_global_load_lds((__attribute__((address_space(1))) void*)g,
                                   (__attribute__((address_space(3))) void*)l, 16, 0, 0);
}

// ---------------- cast fp32 -> bf16 ----------------
__global__ __launch_bounds__(256) void cast_f32_bf16(const float* __restrict__ in,
                                                     ushort_t* __restrict__ out, int n) {
  int i = (blockIdx.x * 256 + threadIdx.x) * 4;
  if (i >= n) return;
  float4 v = *(const float4*)(in + i);
  ushort4 o;
  o.x = f2bf(v.x); o.y = f2bf(v.y); o.z = f2bf(v.z); o.w = f2bf(v.w);
  *(ushort4*)(out + i) = o;
}

// ---------------- generic NT GEMM: C[M,N] = A[M,K] * B[N,K]^T ----------------
// MODE 0: fp32 out, +bias0 (fc3) | MODE 1: bf16 out, tanh (fc1) |
// MODE 2: chunked gx (chunk = 1<<TLB steps): A rows are (b, t0+tl) of f [B,T,H];
//         scatter to gxc[tl][wg][b][g*16+u]
template <int MODE, int TLB>
__global__ __launch_bounds__(256) void gemm_nt(const short* __restrict__ A,
                                               const short* __restrict__ Bm,
                                               const float* __restrict__ bias0,
                                               const float* __restrict__ bias1,
                                               void* __restrict__ Cout,
                                               int M, int N, int K, int t0) {
  __shared__ short As[128 * 32];
  __shared__ short Bs[128 * 32];
  const int tid = threadIdx.x;
  const int wave = tid >> 6, lane = tid & 63;
  const int m0 = blockIdx.y * 128, n0 = blockIdx.x * 128;
  const int wr = wave >> 1, wc = wave & 1;

  f32x4 zero = {0.f, 0.f, 0.f, 0.f};
  f32x4 acc[4][4];
#pragma unroll
  for (int i = 0; i < 4; ++i)
#pragma unroll
    for (int j = 0; j < 4; ++j) acc[i][j] = zero;

  const int lrow = lane >> 2;
  const int lk = (lane & 3) * 8;

  for (int kt = 0; kt < K; kt += 32) {
#pragma unroll
    for (int c = 0; c < 2; ++c) {
      int q = wave + 4 * c;
      int row = m0 + q * 16 + lrow;
      long arow = (MODE == 2) ? ((long)(row >> TLB) * NTT + t0 + (row & ((1 << TLB) - 1)))
                              : (long)row;
      gload_lds16(A + arow * K + kt + lk, As + q * 512);
      gload_lds16(Bm + (long)(n0 + q * 16 + lrow) * K + kt + lk, Bs + q * 512);
    }
    __syncthreads();

    bf16x8 av[4], bv[4];
#pragma unroll
    for (int i = 0; i < 4; ++i) {
      int row = wr * 64 + i * 16 + (lane & 15);
      av[i] = *(const bf16x8*)(As + row * 32 + (lane >> 4) * 8);
    }
#pragma unroll
    for (int j = 0; j < 4; ++j) {
      int col = wc * 64 + j * 16 + (lane & 15);
      bv[j] = *(const bf16x8*)(Bs + col * 32 + (lane >> 4) * 8);
    }
#pragma unroll
    for (int i = 0; i < 4; ++i)
#pragma unroll
      for (int j = 0; j < 4; ++j)
        acc[i][j] = __builtin_amdgcn_mfma_f32_16x16x32_bf16(av[i], bv[j], acc[i][j], 0, 0, 0);
    __syncthreads();
  }

  const int fq = lane >> 4, fr = lane & 15;
#pragma unroll
  for (int i = 0; i < 4; ++i) {
#pragma unroll
    for (int j = 0; j < 4; ++j) {
      int gcol = n0 + wc * 64 + j * 16 + fr;
      float bsum = bias0[gcol];
      if (MODE == 2) bsum += bias1[gcol];
#pragma unroll
      for (int r = 0; r < 4; ++r) {
        int gm = m0 + wr * 64 + i * 16 + fq * 4 + r;
        float v = acc[i][j][r] + bsum;
        if (MODE == 0) {
          ((float*)Cout)[(long)gm * N + gcol] = v;
        } else if (MODE == 1) {
          ((ushort_t*)Cout)[(long)gm * N + gcol] = f2bf(tanhf(v));
        } else {
          int b = gm >> TLB, tl = gm & ((1 << TLB) - 1);
          int wgp = (gcol >> 4) & 63, g = gcol >> 10, u = gcol & 15;
          ((ushort_t*)Cout)[((((long)tl * 64 + wgp) * 64 + b) << 6) + g * 16 + u] = f2bf(v);
        }
      }
    }
  }
}

// ---------------- persistent LSTM scan (one chunk of C=1<<TLB timesteps) ----------------
// R7 structure verbatim (best measured: 6.5 us/step). 64 WGs x 512 threads.
// WG owns 16 hidden units. Waves: g = K-half (512 cols), w2 = batch group (16 b).
// Each wave reads a disjoint 16KB h slice; K-half partials combined via pre[].
// Weight LDS fragment-ordered (conflict-free). Grid sync: per-WG flag lines
// (128B stride), wave0 lanes poll all 64; release = s_waitcnt vmcnt(0)
// (payload stores are agent-atomics); one agent-acquire fence per launch.
template <int TLB>
__global__ __launch_bounds__(512, 2) void lstm_scan(const ushort_t* __restrict__ whh,
                                                    const ushort_t* __restrict__ gxc,  // [C][64][NB][64]
                                                    ushort_t* __restrict__ hseq,       // [C+1][NB][NH]
                                                    float* __restrict__ cbuf,          // [NB][NH]
                                                    ushort_t* __restrict__ hs,         // [NB][NTT][NH]
                                                    uint_t* __restrict__ flags,
                                                    int t0, uint_t tbase) {
  constexpr int C = 1 << TLB;
  extern __shared__ char smem[];
  float* pre = (float*)(smem + 64 * NH * 2);  // [64][64] fp32 (16KB)
  const int wg = blockIdx.x, tid = threadIdx.x;
  const int wave = tid >> 6, lane = tid & 63;
  const int fq = lane >> 4, fr = lane & 15;
  const int g = wave >> 2, w2 = wave & 3;

  // stage weights into fragment-ordered LDS:
  // frag[(ksg*4+nt)*64 + fq*16 + fr] <- W[n=nt*16+fr][k=ksg*32+fq*8 ..+8]
  for (int idx = tid; idx < 64 * 128; idx += 512) {
    int n = idx >> 7, kc = idx & 127;  // kc: 16B chunk (8 bf16) along K
    int grow = (n >> 4) * NH + wg * 16 + (n & 15);
    bf16x8 w = *(const bf16x8*)(whh + (long)grow * NH + kc * 8);
    int frag = ((kc >> 2) * 4 + (n >> 4)) * 64 + (kc & 3) * 16 + (n & 15);
    *(bf16x8*)(smem + frag * 16) = w;
  }
  const int cb = tid >> 3, cup = tid & 7;  // thread owns (b=cb, u=2*cup, 2*cup+1)
  float c0, c1;
  if (t0 == 0) {
    uint_t* p = (uint_t*)(hseq + cb * NH + wg * 16 + cup * 2);
    __hip_atomic_store(p, 0u, __ATOMIC_RELAXED, __HIP_MEMORY_SCOPE_AGENT);
    c0 = 0.f; c1 = 0.f;
  } else {
    c0 = cbuf[cb * NH + wg * 16 + cup * 2];
    c1 = cbuf[cb * NH + wg * 16 + cup * 2 + 1];
  }

  const int bb = w2 * 16;          // batch base for this wave
  const int abrow = bb + fr;       // A-frag row (batch)
  const int lane16 = lane * 16;
  f32x4 zero = {0.f, 0.f, 0.f, 0.f};

  ushort_t gxr[16];
  auto prefetch = [&](int tl) {  // g==0 waves only: all 64 n for own batches
#pragma unroll
    for (int nt = 0; nt < 4; ++nt)
#pragma unroll
      for (int r = 0; r < 4; ++r)
        gxr[nt * 4 + r] =
            gxc[((((long)tl * 64 + wg) * 64 + (bb + fq * 4 + r)) << 6) + nt * 16 + fr];
  };
  auto poll = [&](uint_t t) {
    if (tid < 64) {
      uint_t* fp = flags + tid * 32;
      for (;;) {
        uint_t v = __hip_atomic_load(fp, __ATOMIC_RELAXED, __HIP_MEMORY_SCOPE_AGENT);
        if (__all(v >= t)) break;
        __builtin_amdgcn_s_sleep(1);
      }
    }
  };

  // initial barrier: weights staged, h slot0 + c ready
  asm volatile("s_waitcnt vmcnt(0)" ::: "memory");
  __syncthreads();
  if (tid == 0)
    __hip_atomic_store(flags + wg * 32, tbase + 1, __ATOMIC_RELAXED, __HIP_MEMORY_SCOPE_AGENT);
  poll(tbase + 1);
  // one agent acquire per chunk: drop stale L1/L2 lines of reused hseq slots
  __builtin_amdgcn_fence(__ATOMIC_ACQUIRE, "agent");
  __syncthreads();
  if (g == 0) prefetch(0);

  for (int tl = 0; tl < C; ++tl) {
    const ushort_t* hc = hseq + (size_t)tl * (NB * NH);
    // bulk-stage this wave's disjoint K-half slice: 16 x 16B loads in flight
    bf16x8 areg[16];
#pragma unroll
    for (int ks = 0; ks < 16; ++ks) {
      int ksg = g * 16 + ((ks + wg) & 15);  // per-WG rotation de-bursts LLC lines
      areg[ks] = *(const bf16x8*)(hc + abrow * NH + ksg * 32 + fq * 8);
    }
    __builtin_amdgcn_sched_barrier(0);

    f32x4 acc[4] = {zero, zero, zero, zero};
#pragma unroll
    for (int ks = 0; ks < 16; ++ks) {
      int ksg = g * 16 + ((ks + wg) & 15);
#pragma unroll
      for (int nt = 0; nt < 4; ++nt) {
        bf16x8 w = *(const bf16x8*)(smem + ((ksg * 4 + nt) << 10) + lane16);
        acc[nt] = __builtin_amdgcn_mfma_f32_16x16x32_bf16(areg[ks], w, acc[nt], 0, 0, 0);
      }
    }
    // combine K-half partials via pre[]
    if (g == 1) {
#pragma unroll
      for (int nt = 0; nt < 4; ++nt)
#pragma unroll
        for (int r = 0; r < 4; ++r)
          pre[(bb + fq * 4 + r) * 64 + nt * 16 + fr] = acc[nt][r];
    }
    __syncthreads();
    if (g == 0) {
#pragma unroll
      for (int nt = 0; nt < 4; ++nt)
#pragma unroll
        for (int r = 0; r < 4; ++r) {
          int ii = (bb + fq * 4 + r) * 64 + nt * 16 + fr;
          pre[ii] = pre[ii] + acc[nt][r] + bf2f(gxr[nt * 4 + r]);
        }
    }
    __syncthreads();
    // gates + state update for (cb, u0, u1)
    float h01[2];
#pragma unroll
    for (int k = 0; k < 2; ++k) {
      int u = cup * 2 + k;
      float xi = pre[cb * 64 + 0 * 16 + u];
      float xf = pre[cb * 64 + 1 * 16 + u];
      float xg = pre[cb * 64 + 2 * 16 + u];
      float xo = pre[cb * 64 + 3 * 16 + u];
      float ig = 1.f / (1.f + __expf(-xi));
      float fg = 1.f / (1.f + __expf(-xf));
      float gg = tanh_f(xg);
      float og = 1.f / (1.f + __expf(-xo));
      float& c = k ? c1 : c0;
      c = fg * c + ig * gg;
      h01[k] = og * tanh_f(c);
    }
    uint_t hpack = (uint_t)f2bf(h01[0]) | ((uint_t)f2bf(h01[1]) << 16);
    uint_t* hdst = (uint_t*)(hseq + (size_t)(tl + 1) * (NB * NH) + cb * NH + wg * 16 + cup * 2);
    __hip_atomic_store(hdst, hpack, __ATOMIC_RELAXED, __HIP_MEMORY_SCOPE_AGENT);
    if (tl == C - 1) {  // hand h(final) to next chunk's slot 0
      uint_t* h0 = (uint_t*)(hseq + cb * NH + wg * 16 + cup * 2);
      __hip_atomic_store(h0, hpack, __ATOMIC_RELAXED, __HIP_MEMORY_SCOPE_AGENT);
    }

    // ---- grid barrier: vmcnt-drain release ----
    asm volatile("s_waitcnt vmcnt(0)" ::: "memory");  // h atomic stores acked at LLC
    __syncthreads();
    uint_t t = tbase + 2 + tl;
    if (tid == 0)
      __hip_atomic_store(flags + wg * 32, t, __ATOMIC_RELAXED, __HIP_MEMORY_SCOPE_AGENT);
    // off-critical-path work overlapped with the wait:
    *(uint_t*)(hs + ((size_t)cb * NTT + t0 + tl) * NH + wg * 16 + cup * 2) = hpack;
    if (g == 0 && tl + 1 < C) prefetch(tl + 1);
    poll(t);
    __syncthreads();
    asm volatile("" ::: "memory");
  }
  // persist c for next chunk
  cbuf[cb * NH + wg * 16 + cup * 2] = c0;
  cbuf[cb * NH + wg * 16 + cup * 2 + 1] = c1;
}

// ---------------- host ----------------
extern "C" void kernel_launch(void* const* d_in, const int* in_sizes, int n_in,
                              void* d_out, int out_size, void* d_ws, size_t ws_size,
                              hipStream_t stream) {
  const float* x = (const float*)d_in[0];
  const float* w1 = (const float*)d_in[1];
  const float* b1 = (const float*)d_in[2];
  const float* w_ih = (const float*)d_in[3];
  const float* w_hh = (const float*)d_in[4];
  const float* b_ih = (const float*)d_in[5];
  const float* b_hh = (const float*)d_in[6];
  const float* w3 = (const float*)d_in[7];
  const float* b3 = (const float*)d_in[8];

  char* ws = (char*)d_ws;
  size_t off = 0;
  auto alloc = [&](size_t bytes) {
    char* p = ws + off;
    off += (bytes + 255) & ~(size_t)255;
    return p;
  };
  ushort_t* w1b = (ushort_t*)alloc(sizeof(ushort_t) * NH * NI);
  ushort_t* wihb = (ushort_t*)alloc(sizeof(ushort_t) * NG * NH);
  ushort_t* whhb = (ushort_t*)alloc(sizeof(ushort_t) * NG * NH);
  ushort_t* w3b = (ushort_t*)alloc(sizeof(ushort_t) * NA * NH);
  ushort_t* fb = (ushort_t*)alloc(sizeof(ushort_t) * (size_t)NB * NTT * NH);  // f, then hs (in-place)
  float* cbuf = (float*)alloc(sizeof(float) * NB * NH);
  uint_t* flags = (uint_t*)alloc(sizeof(uint_t) * 64 * 32);
  size_t off_small = off;
  // optional big-chunk gx buffer (C=128): 128*64*64*64*2B = 67MB in ws
  ushort_t* gxc_big = (ushort_t*)alloc(sizeof(ushort_t) * (size_t)128 * 64 * NB * 64);
  bool big = (off <= ws_size);
  if (!big && off_small > ws_size) {
    hipMemsetAsync(d_out, 0xFF, 256, stream);  // NaN sentinel: ws too small even for base
    return;
  }

  // scratch carved out of d_out (dead before fc3 writes d_out):
  ushort_t* xb = (ushort_t*)d_out;                           // bf16 x for fc1 (33.5MB)
  ushort_t* hseq = (ushort_t*)d_out;                         // [C+1][NB][NH] (reuses xb; C=128 -> 16.9MB)
  ushort_t* gxc_small = (ushort_t*)d_out + (size_t)NB * NTT * NI;  // [64][64][NB][64] (33.5MB)

  auto cast = [&](const float* src, ushort_t* dst, int n) {
    cast_f32_bf16<<<dim3((n / 4 + 255) / 256), dim3(256), 0, stream>>>(src, dst, n);
  };
  cast(x, xb, NB * NTT * NI);
  cast(w1, w1b, NH * NI);
  cast(w_ih, wihb, NG * NH);
  cast(w_hh, whhb, NG * NH);
  cast(w3, w3b, NA * NH);

  // fc1 + tanh -> f (bf16)
  gemm_nt<1, 6><<<dim3(NH / 128, NB * NTT / 128), dim3(256), 0, stream>>>(
      (const short*)xb, (const short*)w1b, b1, nullptr, fb, NB * NTT, NH, NI, 0);

  hipMemsetAsync(flags, 0, sizeof(uint_t) * 64 * 32, stream);
  int ldsz = 64 * NH * 2 + 64 * 64 * 4;
  hipFuncSetAttribute(reinterpret_cast<const void*>(&lstm_scan<6>),
                      hipFuncAttributeMaxDynamicSharedMemorySize, ldsz);
  hipFuncSetAttribute(reinterpret_cast<const void*>(&lstm_scan<7>),
                      hipFuncAttributeMaxDynamicSharedMemorySize, ldsz);

  if (big) {
    // C = 128: 4 chunks, gxc in ws
    for (int chunk = 0; chunk < NTT / 128; ++chunk) {
      int t0 = chunk * 128;
      gemm_nt<2, 7><<<dim3(NG / 128, NB * 128 / 128), dim3(256), 0, stream>>>(
          (const short*)fb, (const short*)wihb, b_ih, b_hh, gxc_big, NB * 128, NG, NH, t0);
      lstm_scan<7><<<dim3(64), dim3(512), ldsz, stream>>>(
          whhb, gxc_big, hseq, cbuf, fb, flags, t0, (uint_t)(chunk * 129));
    }
  } else {
    // C = 64: 8 chunks, gxc in d_out (proven fallback)
    for (int chunk = 0; chunk < NTT / 64; ++chunk) {
      int t0 = chunk * 64;
      gemm_nt<2, 6><<<dim3(NG / 128, NB * 64 / 128), dim3(256), 0, stream>>>(
          (const short*)fb, (const short*)wihb, b_ih, b_hh, gxc_small, NB * 64, NG, NH, t0);
      lstm_scan<6><<<dim3(64), dim3(512), ldsz, stream>>>(
          whhb, gxc_small, hseq, cbuf, fb, flags, t0, (uint_t)(chunk * 65));
    }
  }

  // fc3 head -> d_out (fp32)
  gemm_nt<0, 6><<<dim3(NA / 128, NB * NTT / 128), dim3(256), 0, stream>>>(
      (const short*)fb, (const short*)w3b, b3, nullptr, d_out, NB * NTT, NA, NH, 0);
}